// Round 7
// baseline (469.058 us; speedup 1.0000x reference)
//
#include <hip/hip_runtime.h>

// ---------------------------------------------------------------------------
// CrossAttention (BLT-style patch cross-attention), MI355X gfx950
// B=2, S=4096, P=1024, D=1024, H=16, dh=64
//
// Round 14 (attention wave-pair patch-split):
//   - attn: 8 waves / 512 thr per 128-q block. Waves w and w+4 own the same
//     32 q-rows and split each 64-patch tile by half (role = at):
//     per wave per tile 4 QK MFMA + 16 exp + 2 pack frags + 4 PV MFMA
//     (half of R10's serial path), 2x resident waves.
//     oacc/lsum are linear in p -> one end-of-block LDS combine (2 phases
//     reusing Ks, 16KB each), no per-tile cost.
//   - staging spread over 8 waves (1 K-chunk + 1 V-chunk each, vmcnt(2))
//   - __launch_bounds__(512,6): VGPR cap ~85 -> 3 blocks/CU (24 waves/CU)
//   - GEMMs + convert unchanged from R13 (wide 128x256 tiles, measured safe)
// ---------------------------------------------------------------------------

#define B_ 2
#define S_ 4096
#define P_ 1024
#define D_ 1024
#define H_ 16
#define DH_ 64

#define NCONV 14336   /* convert blocks: (2097152+524288+4*262144)/256 */

typedef __attribute__((ext_vector_type(8))) short short8;
typedef __attribute__((ext_vector_type(4))) float f32x4;
typedef __attribute__((ext_vector_type(16))) float f32x16;

#define KSCALE 0.18033688011112042f  /* 1/sqrt(64) * log2(e) */

#if __has_builtin(__builtin_amdgcn_exp2f)
#define EXP2(x) __builtin_amdgcn_exp2f(x)
#else
#define EXP2(x) exp2f(x)
#endif

static __device__ __forceinline__ unsigned short f2bf(float f) {
    unsigned int u = __float_as_uint(f);
    u += 0x7FFFu + ((u >> 16) & 1u);   // round-to-nearest-even
    return (unsigned short)(u >> 16);
}

// packed f32->bf16 pair (RTNE), no builtin on gfx950
static __device__ __forceinline__ unsigned int cvtpk(float lo, float hi) {
    unsigned int r;
    asm("v_cvt_pk_bf16_f32 %0, %1, %2" : "=v"(r) : "v"(lo), "v"(hi));
    return r;
}

// x' = [x.row0, y.row0] ; y' = [x.row1, y.row1]  (rows = 32-lane halves)
static __device__ __forceinline__ void plswap(unsigned int& x, unsigned int& y) {
    asm volatile("v_permlane32_swap_b32 %0, %1" : "+v"(x), "+v"(y));
}

// async 16B global -> LDS (wave-uniform lds base + lane*16; global per-lane)
static __device__ __forceinline__ void gll16(const unsigned short* g,
                                             const unsigned short* l) {
    __builtin_amdgcn_global_load_lds(
        (const __attribute__((address_space(1))) unsigned int*)g,
        (__attribute__((address_space(3))) unsigned int*)l,
        16, 0, 0);
}

// ---------------------------------------------------------------------------
// fused fp32 -> bf16 conversion of all six tensors + cumsum (single launch)
// ---------------------------------------------------------------------------
__global__ __launch_bounds__(256) void xattn_convert_all(
    const float* __restrict__ queries, const float* __restrict__ patches,
    const float* __restrict__ wq, const float* __restrict__ wk,
    const float* __restrict__ wv, const float* __restrict__ wo,
    unsigned short* __restrict__ qb, unsigned short* __restrict__ pb,
    unsigned short* __restrict__ wqb, unsigned short* __restrict__ wkb,
    unsigned short* __restrict__ wvb, unsigned short* __restrict__ wob,
    const int* __restrict__ bounds, int* __restrict__ pidx) {
    if (blockIdx.x >= NCONV) {
        // ---- cumsum path: one block per batch, 256 threads x 16 elems ----
        __shared__ int sdata[256];
        int b = blockIdx.x - NCONV;
        int t = threadIdx.x;
        const int* src = bounds + b * S_ + t * 16;
        int vals[16];
        int run = 0;
#pragma unroll
        for (int i = 0; i < 16; ++i) { run += src[i]; vals[i] = run; }
        sdata[t] = run;
        __syncthreads();
        for (int off = 1; off < 256; off <<= 1) {
            int v = (t >= off) ? sdata[t - off] : 0;
            __syncthreads();
            sdata[t] += v;
            __syncthreads();
        }
        int prefix = (t > 0) ? sdata[t - 1] : 0;
        int* dst = pidx + b * S_ + t * 16;
#pragma unroll
        for (int i = 0; i < 16; ++i) dst[i] = prefix + vals[i];
        return;
    }
    // ---- convert path ----
    const int NQ = (B_ * S_ * D_) / 4;      // 2097152
    const int NP = (B_ * P_ * D_) / 4;      // 524288
    const int NW = (D_ * D_) / 4;           // 262144
    int i = blockIdx.x * 256 + threadIdx.x;
    const float* src;
    unsigned short* dst;
    int j;
    if (i < NQ) { src = queries; dst = qb; j = i; }
    else if (i < NQ + NP) { src = patches; dst = pb; j = i - NQ; }
    else {
        int k = i - NQ - NP;
        int wsel = k >> 18;                  // NW = 2^18
        j = k & (NW - 1);
        if (wsel == 0) { src = wq; dst = wqb; }
        else if (wsel == 1) { src = wk; dst = wkb; }
        else if (wsel == 2) { src = wv; dst = wvb; }
        else { src = wo; dst = wob; }
    }
    float4 v = ((const float4*)src)[j];
    ushort4 o;
    o.x = f2bf(v.x); o.y = f2bf(v.y); o.z = f2bf(v.z); o.w = f2bf(v.w);
    ((ushort4*)dst)[j] = o;
}

// ---------------------------------------------------------------------------
// Fused QKV projection: 128Mx256N tile, 8 waves, dbuf gll staging + counted
// vmcnt(3), XOR-swizzled LDS, BK=32. (unchanged from R13)
// Grid dim3(4, 96): y<64 -> Q-proj; y in [64,80) -> K-proj (frag-linear Kf);
//                   y in [80,96) -> V-proj (frag-linear Vf)
// Fragment-linear layouts (per b,h,ptile of 64 patches; 4096 shorts each):
//   Kf: [at(2)][ks(4)][lane(64)][j(8)]   lane=((k>>3)&1)*32+(p&31), j=k&7
//   Vf: [dt(2)][ps(4)][lane(64)][j(8)]   lane=((p>>3)&1)*32+(d&31), j=p&7
// ---------------------------------------------------------------------------
__global__ __launch_bounds__(512) void xattn_gemm_qkv(
    const unsigned short* __restrict__ qb, const unsigned short* __restrict__ pb,
    const unsigned short* __restrict__ wqb, const unsigned short* __restrict__ wkb,
    const unsigned short* __restrict__ wvb,
    const float* __restrict__ bq, const float* __restrict__ bk,
    const float* __restrict__ bv,
    unsigned short* __restrict__ Qout, unsigned short* __restrict__ Kout,
    unsigned short* __restrict__ Vout) {
    const int K = 1024, N = 1024;
    const int byy = blockIdx.y;
    int z, my;
    if (byy < 64)      { z = 0; my = byy; }
    else if (byy < 80) { z = 1; my = byy - 64; }
    else               { z = 2; my = byy - 80; }
    const unsigned short* A = (z == 0) ? qb : pb;
    const unsigned short* W = (z == 0) ? wqb : ((z == 1) ? wkb : wvb);
    const float* bias = (z == 0) ? bq : ((z == 1) ? bk : bv);

    __shared__ unsigned short As[2][128 * 32];
    __shared__ unsigned short Bs[2][256 * 32];

    const int m0 = my * 128;
    const int n0 = blockIdx.x * 256;
    const int t = threadIdx.x;
    const int w = t >> 6;
    const int l = t & 63;
    const int fr = l & 15, fq = l >> 4;
    const int wr = w >> 2, wc = w & 3;

    const int r0s = t >> 2;
    const int csw = ((t & 3) ^ ((t >> 3) & 3)) * 8;   // pre-swizzled source
    const unsigned short* Ap0 = A + (size_t)(m0 + r0s) * K + csw;
    const unsigned short* Wp0 = W + (size_t)(n0 + r0s) * K + csw;
    const unsigned short* Wp1 = W + (size_t)(n0 + 128 + r0s) * K + csw;

    const int gsw = (fq ^ ((fr >> 1) & 3)) * 8;       // swizzled read granule

    f32x4 acc[4][4];
#pragma unroll
    for (int i = 0; i < 4; ++i)
#pragma unroll
        for (int j = 0; j < 4; ++j) acc[i][j] = (f32x4){0.f, 0.f, 0.f, 0.f};

    // prologue: stage K-step 0 into buffer 0
    gll16(Ap0, &As[0][w * 512]);
    gll16(Wp0, &Bs[0][w * 512]);
    gll16(Wp1, &Bs[0][4096 + w * 512]);

    for (int kt = 0; kt < 32; ++kt) {
        __builtin_amdgcn_s_barrier();     // prev iter's readers done
        if (kt + 1 < 32) {
            const int nb = (kt + 1) & 1;
            const int ks = (kt + 1) * 32;
            gll16(Ap0 + ks, &As[nb][w * 512]);
            gll16(Wp0 + ks, &Bs[nb][w * 512]);
            gll16(Wp1 + ks, &Bs[nb][4096 + w * 512]);
            asm volatile("s_waitcnt vmcnt(3)" ::: "memory");
        } else {
            asm volatile("s_waitcnt vmcnt(0)" ::: "memory");
        }
        __builtin_amdgcn_sched_barrier(0);
        __builtin_amdgcn_s_barrier();     // all waves' step-kt stage complete

        const unsigned short* Ac = As[kt & 1];
        const unsigned short* Bc = Bs[kt & 1];
        short8 af[4], bf[4];
#pragma unroll
        for (int i = 0; i < 4; ++i)
            af[i] = *(const short8*)&Ac[(wr * 64 + i * 16 + fr) * 32 + gsw];
#pragma unroll
        for (int j = 0; j < 4; ++j)
            bf[j] = *(const short8*)&Bc[(wc * 64 + j * 16 + fr) * 32 + gsw];
        __builtin_amdgcn_s_setprio(1);
#pragma unroll
        for (int i = 0; i < 4; ++i)
#pragma unroll
            for (int j = 0; j < 4; ++j)
                acc[i][j] = __builtin_amdgcn_mfma_f32_16x16x32_bf16(af[i], bf[j], acc[i][j], 0, 0, 0);
        __builtin_amdgcn_s_setprio(0);
    }

#pragma unroll
    for (int j = 0; j < 4; ++j) {
        int n = n0 + wc * 64 + j * 16 + fr;
        float bvv = bias[n];
#pragma unroll
        for (int i = 0; i < 4; ++i) {
            int mbase = m0 + wr * 64 + i * 16 + fq * 4;
#pragma unroll
            for (int r = 0; r < 4; ++r) {
                float val = acc[i][j][r] + bvv;
                int m = mbase + r;
                if (z == 0) {
                    Qout[(size_t)m * N + n] = f2bf(val * KSCALE);
                } else if (z == 1) {
                    int bb = m >> 10, p = m & (P_ - 1);
                    int hh = n >> 6, k = n & 63;
                    size_t base = ((size_t)((bb * H_ + hh) * 16 + (p >> 6))) * 4096;
                    int off = (((p >> 5) & 1) * 4 + (k >> 4)) * 512 +
                              (((k >> 3) & 1) * 32 + (p & 31)) * 8 + (k & 7);
                    Kout[base + off] = f2bf(val);
                } else {
                    int bb = m >> 10, p = m & (P_ - 1);
                    int hh = n >> 6, d = n & 63;
                    size_t base = ((size_t)((bb * H_ + hh) * 16 + (p >> 6))) * 4096;
                    int off = ((d >> 5) * 4 + ((p >> 4) & 3)) * 512 +
                              ((((p >> 3) & 1) * 32) + (d & 31)) * 8 + (p & 7);
                    Vout[base + off] = f2bf(val);
                }
            }
        }
    }
}

// ---------------------------------------------------------------------------
// O projection: 128Mx256N tile, 8 waves, dbuf gll staging + counted vmcnt(3),
// XOR-swizzled LDS, fp32 out. (unchanged from R13)
// ---------------------------------------------------------------------------
__global__ __launch_bounds__(512) void xattn_gemm_o(
    const unsigned short* __restrict__ A,
    const unsigned short* __restrict__ W,
    const float* __restrict__ bias,
    float* __restrict__ Cout) {
    const int K = 1024, N = 1024;
    __shared__ unsigned short As[2][128 * 32];
    __shared__ unsigned short Bs[2][256 * 32];

    const int m0 = blockIdx.y * 128;
    const int n0 = blockIdx.x * 256;
    const int t = threadIdx.x;
    const int w = t >> 6;
    const int l = t & 63;
    const int fr = l & 15, fq = l >> 4;
    const int wr = w >> 2, wc = w & 3;

    const int r0s = t >> 2;
    const int csw = ((t & 3) ^ ((t >> 3) & 3)) * 8;   // pre-swizzled source
    const unsigned short* Ap0 = A + (size_t)(m0 + r0s) * K + csw;
    const unsigned short* Wp0 = W + (size_t)(n0 + r0s) * K + csw;
    const unsigned short* Wp1 = W + (size_t)(n0 + 128 + r0s) * K + csw;

    const int gsw = (fq ^ ((fr >> 1) & 3)) * 8;       // swizzled read granule

    f32x4 acc[4][4];
#pragma unroll
    for (int i = 0; i < 4; ++i)
#pragma unroll
        for (int j = 0; j < 4; ++j) acc[i][j] = (f32x4){0.f, 0.f, 0.f, 0.f};

    // prologue: stage K-step 0 into buffer 0
    gll16(Ap0, &As[0][w * 512]);
    gll16(Wp0, &Bs[0][w * 512]);
    gll16(Wp1, &Bs[0][4096 + w * 512]);

    for (int kt = 0; kt < 32; ++kt) {
        __builtin_amdgcn_s_barrier();
        if (kt + 1 < 32) {
            const int nb = (kt + 1) & 1;
            const int ks = (kt + 1) * 32;
            gll16(Ap0 + ks, &As[nb][w * 512]);
            gll16(Wp0 + ks, &Bs[nb][w * 512]);
            gll16(Wp1 + ks, &Bs[nb][4096 + w * 512]);
            asm volatile("s_waitcnt vmcnt(3)" ::: "memory");
        } else {
            asm volatile("s_waitcnt vmcnt(0)" ::: "memory");
        }
        __builtin_amdgcn_sched_barrier(0);
        __builtin_amdgcn_s_barrier();

        const unsigned short* Ac = As[kt & 1];
        const unsigned short* Bc = Bs[kt & 1];
        short8 af[4], bf[4];
#pragma unroll
        for (int i = 0; i < 4; ++i)
            af[i] = *(const short8*)&Ac[(wr * 64 + i * 16 + fr) * 32 + gsw];
#pragma unroll
        for (int j = 0; j < 4; ++j)
            bf[j] = *(const short8*)&Bc[(wc * 64 + j * 16 + fr) * 32 + gsw];
        __builtin_amdgcn_s_setprio(1);
#pragma unroll
        for (int i = 0; i < 4; ++i)
#pragma unroll
            for (int j = 0; j < 4; ++j)
                acc[i][j] = __builtin_amdgcn_mfma_f32_16x16x32_bf16(af[i], bf[j], acc[i][j], 0, 0, 0);
        __builtin_amdgcn_s_setprio(0);
    }

#pragma unroll
    for (int j = 0; j < 4; ++j) {
        int n = n0 + wc * 64 + j * 16 + fr;
        float bvv = bias[n];
#pragma unroll
        for (int i = 0; i < 4; ++i) {
            int mbase = m0 + wr * 64 + i * 16 + fq * 4;
#pragma unroll
            for (int r = 0; r < 4; ++r)
                Cout[(size_t)(mbase + r) * N + n] = acc[i][j][r] + bvv;
        }
    }
}

// ---------------------------------------------------------------------------
// MFMA flash attention, round 14: wave-pair patch-split.
// 8 waves x 512 thr per 128-q block. Wave w: q-rows (w&3)*32.., role = w>>2.
// Per 64-patch tile, per wave (its 32-patch half only):
//   S^T = mfma(K[role],Q): 4 MFMA32; exp2+mask+lsum on 16 regs;
//   pack 2 pa frags (8 cvtpk + 4 permlane); PV: 4 MFMA32 (2 dt x 2 ps).
// oacc/lsum linear in p -> end-of-block LDS combine (2 x 16KB phases in Ks).
// All LDS reads lane-linear ds_read_b128 (zero bank conflicts by design).
// ---------------------------------------------------------------------------
__global__ __launch_bounds__(512, 6) void xattn_attn_mfma(
    const unsigned short* __restrict__ Qb,   // [B*S][D] bf16 (pre-scaled)
    const unsigned short* __restrict__ Kf,   // frag-linear (see gemm_qkv)
    const unsigned short* __restrict__ Vf,   // frag-linear
    const int* __restrict__ pidx,
    unsigned short* __restrict__ Ob) {       // [B*S][D] bf16
    __shared__ unsigned short Ks[2][4096];
    __shared__ unsigned short Vs[2][4096];

    const int q0 = (31 - blockIdx.x) * 128;  // LPT: heavy blocks first
    const int h = blockIdx.y;
    const int b = blockIdx.z;
    const int t = threadIdx.x;
    const int w = t >> 6, l = t & 63;
    const int lq = l & 31, lh = l >> 5;
    const int wq4 = w & 3, role = w >> 2;    // q-subblock, patch-half role
    const int qw = q0 + wq4 * 32;

    // Q B-frags (col = lq, k = ks*16 + lh*8 + j); both roles load same rows
    const unsigned short* qrow =
        Qb + (size_t)(b * S_ + qw + lq) * D_ + h * DH_ + lh * 8;
    short8 qf[4];
#pragma unroll
    for (int ks = 0; ks < 4; ++ks) qf[ks] = *(const short8*)(qrow + ks * 16);

    const int prow = pidx[b * S_ + qw + lq];        // this lane's q row
    const int limit = pidx[b * S_ + q0 + 127];      // monotone in s
    const int ntiles = (min(limit, P_ - 1) + 64) >> 6;
    const int nfull = (pidx[b * S_ + q0] + 1) >> 6; // tiles needing no mask

    float l4[4] = {0.f, 0.f, 0.f, 0.f};
    f32x16 oacc[2] = {{}, {}};

    // staging: wave w moves chunk w (1KB) of each 8KB frag tile
    const unsigned short* kfb =
        Kf + (size_t)((b * H_ + h) * 16) * 4096 + w * 512 + l * 8;
    const unsigned short* vfb =
        Vf + (size_t)((b * H_ + h) * 16) * 4096 + w * 512 + l * 8;

    // prologue: stage tile 0 into buffer 0 (2 loads/wave)
    gll16(kfb, &Ks[0][w * 512]);
    gll16(vfb, &Vs[0][w * 512]);

    for (int kt = 0; kt < ntiles; ++kt) {
        // B1: all waves done reading buf[kt&1 ^1] -> safe to refill
        __builtin_amdgcn_s_barrier();
        if (kt + 1 < ntiles) {
            const int nb = (kt + 1) & 1;
            gll16(kfb + (size_t)(kt + 1) * 4096, &Ks[nb][w * 512]);
            gll16(vfb + (size_t)(kt + 1) * 4096, &Vs[nb][w * 512]);
            // wait only for tile kt's 2 loads; kt+1's stay in flight
            asm volatile("s_waitcnt vmcnt(2)" ::: "memory");
        } else {
            asm volatile("s_waitcnt vmcnt(0)" ::: "memory");
        }
        __builtin_amdgcn_sched_barrier(0);
        // B2: every wave's tile-kt stage is complete
        __builtin_amdgcn_s_barrier();

        const unsigned short* Kc = Ks[kt & 1];
        const unsigned short* Vc = Vs[kt & 1];
        const int c0 = kt * 64;

        // S^T = K . Q^T, this wave's patch half only (rows p, cols q = lq)
        f32x16 sa = {};
        __builtin_amdgcn_s_setprio(1);
#pragma unroll
        for (int ks = 0; ks < 4; ++ks) {
            short8 kfr = *(const short8*)&Kc[(role * 4 + ks) * 512 + l * 8];
            sa = __builtin_amdgcn_mfma_f32_32x32x16_bf16(kfr, qf[ks], sa, 0, 0, 0);
        }
        __builtin_amdgcn_s_setprio(0);

        // exp2 + boundary mask + lsum (p = c0 + role*32 + crow(r,lh))
        if (kt >= nfull) {
#pragma unroll
            for (int r = 0; r < 16; ++r) {
                const int pg = c0 + role * 32 + (r & 3) + 8 * (r >> 2) + 4 * lh;
                float p = EXP2(sa[r]);
                p = (pg > prow) ? 0.f : p;
                sa[r] = p;
                l4[r & 3] += p;
            }
        } else {
#pragma unroll
            for (int r = 0; r < 16; ++r) {
                float p = EXP2(sa[r]);
                sa[r] = p;
                l4[r & 3] += p;
            }
        }

        // pack P into PV A-frags (this half's 2 ps steps)
        short8 pa[2];
#pragma unroll
        for (int psl = 0; psl < 2; ++psl) {
            const int rA = psl * 8;
            unsigned int X0 = cvtpk(sa[rA + 0], sa[rA + 1]);
            unsigned int Y0 = cvtpk(sa[rA + 4], sa[rA + 5]);
            unsigned int X1 = cvtpk(sa[rA + 2], sa[rA + 3]);
            unsigned int Y1 = cvtpk(sa[rA + 6], sa[rA + 7]);
            plswap(X0, Y0);   // X0 -> word m=0, Y0 -> word m=2
            plswap(X1, Y1);   // X1 -> word m=1, Y1 -> word m=3
            uint4 u = {X0, X1, Y0, Y1};
            pa[psl] = *(short8*)&u;
        }

        // PV partial: O[q][d] += P_half . V_half
        __builtin_amdgcn_s_setprio(1);
#pragma unroll
        for (int dt = 0; dt < 2; ++dt)
#pragma unroll
            for (int psl = 0; psl < 2; ++psl) {
                short8 vfr = *(const short8*)
                    &Vc[(dt * 4 + role * 2 + psl) * 512 + l * 8];
                oacc[dt] = __builtin_amdgcn_mfma_f32_32x32x16_bf16(pa[psl], vfr, oacc[dt], 0, 0, 0);
            }
        __builtin_amdgcn_s_setprio(0);
    }

    // ---- cross-role combine (oacc and lsum are linear in p) ----
    float lsum = (l4[0] + l4[1]) + (l4[2] + l4[3]);  // partial: 16 p-values
    float* cf = (float*)&Ks[0][0];                   // 4096 floats (16KB)
    float* lf = (float*)&Vs[0][0];                   // 256 floats
    const int ci = wq4 * 64 + l;

    __builtin_amdgcn_s_barrier();          // all waves done with K/V LDS
    if (role) {
#pragma unroll
        for (int r = 0; r < 16; ++r) cf[ci * 16 + r] = oacc[0][r];
        lf[ci] = lsum;
    }
    __builtin_amdgcn_s_barrier();
    if (!role) {
#pragma unroll
        for (int r = 0; r < 16; ++r) oacc[0][r] += cf[ci * 16 + r];
        lsum += lf[ci];
    }
    __builtin_amdgcn_s_barrier();
    if (role) {
#pragma unroll
        for (int r = 0; r < 16; ++r) cf[ci * 16 + r] = oacc[1][r];
    }
    __builtin_amdgcn_s_barrier();
    if (!role) {
#pragma unroll
        for (int r = 0; r < 16; ++r) oacc[1][r] += cf[ci * 16 + r];

        // softmax denominator: own half + partner lane's half
        lsum += __shfl_xor(lsum, 32);
        const float inv = 1.0f / lsum;

        unsigned short* ob = Ob + (size_t)(b * S_ + qw) * D_ + h * DH_;
#pragma unroll
        for (int r = 0; r < 16; ++r) {
            const int qr = (r & 3) + 8 * (r >> 2) + 4 * lh;
            const float invr = __shfl(inv, qr);
            ob[(size_t)qr * D_ + lq] = f2bf(oacc[0][r] * invr);
            ob[(size_t)qr * D_ + 32 + lq] = f2bf(oacc[1][r] * invr);
        }
    }
}

// ---------------------------------------------------------------------------
// launch
// ---------------------------------------------------------------------------
extern "C" void kernel_launch(void* const* d_in, const int* in_sizes, int n_in,
                              void* d_out, int out_size, void* d_ws, size_t ws_size,
                              hipStream_t stream) {
    const float* queries = (const float*)d_in[0];
    const float* patches = (const float*)d_in[1];
    const int* bounds    = (const int*)d_in[2];
    const float* wq = (const float*)d_in[3];
    const float* wk = (const float*)d_in[4];
    const float* wv = (const float*)d_in[5];
    const float* wo = (const float*)d_in[6];
    const float* bq = (const float*)d_in[7];
    const float* bk = (const float*)d_in[8];
    const float* bv = (const float*)d_in[9];
    const float* bo = (const float*)d_in[10];
    float* out = (float*)d_out;

    char* ws = (char*)d_ws;
    unsigned short* qb    = (unsigned short*)(ws + 0);          // 16777216
    unsigned short* pb    = (unsigned short*)(ws + 16777216);   // 4194304
    unsigned short* wqb   = (unsigned short*)(ws + 20971520);   // 2097152
    unsigned short* wkb   = (unsigned short*)(ws + 23068672);
    unsigned short* wvb   = (unsigned short*)(ws + 25165824);
    unsigned short* wob   = (unsigned short*)(ws + 27262976);
    unsigned short* Qbf   = (unsigned short*)(ws + 29360128);   // 16777216
    unsigned short* Kfr   = (unsigned short*)(ws + 46137344);   // 4194304
    unsigned short* Vfr   = (unsigned short*)(ws + 50331648);   // 4194304
    unsigned short* attnb = (unsigned short*)(ws + 54525952);   // 16777216
    int* pidx             = (int*)(ws + 71303168);              // 32768

    // 1. fused converts + cumsum
    xattn_convert_all<<<dim3(NCONV + B_), 256, 0, stream>>>(
        queries, patches, wq, wk, wv, wo, qb, pb, wqb, wkb, wvb, wob,
        bounds, pidx);
    // 2. fused Q/K/V projections (128x256 tiles, K/V emitted frag-linear)
    xattn_gemm_qkv<<<dim3(4, 96), 512, 0, stream>>>(
        qb, pb, wqb, wkb, wvb, bq, bk, bv, Qbf, Kfr, Vfr);
    // 3. MFMA flash attention (wave-pair patch-split, 8 waves)
    xattn_attn_mfma<<<dim3(S_ / 128, H_, B_), 512, 0, stream>>>(
        Qbf, Kfr, Vfr, pidx, attnb);
    // 4. output projection (128x256 tiles, fp32 out)
    xattn_gemm_o<<<dim3(4, 64), 512, 0, stream>>>(attnb, wob, bo, out);
}

// Round 8
// 230.890 us; speedup vs baseline: 2.0315x; 2.0315x over previous
//
#include <hip/hip_runtime.h>

// ---------------------------------------------------------------------------
// CrossAttention (BLT-style patch cross-attention), MI355X gfx950
// B=2, S=4096, P=1024, D=1024, H=16, dh=64
//
// Round 15 (R14 wave-pair split, spill fixed):
//   - attn: identical structure to R14 (8 waves / 512 thr, waves w and w+4
//     split each 64-patch tile by half; end-of-block LDS combine) but
//     __launch_bounds__(512) WITHOUT the min-waves arg. R14's (512,6) capped
//     VGPR at 84 < ~90 needed -> accumulators spilled to scratch (VGPR=40,
//     1 GB scratch traffic, 284 us). Structure itself verified correct.
//   - GEMMs + convert unchanged from R13 (wide 128x256 tiles)
// ---------------------------------------------------------------------------

#define B_ 2
#define S_ 4096
#define P_ 1024
#define D_ 1024
#define H_ 16
#define DH_ 64

#define NCONV 14336   /* convert blocks: (2097152+524288+4*262144)/256 */

typedef __attribute__((ext_vector_type(8))) short short8;
typedef __attribute__((ext_vector_type(4))) float f32x4;
typedef __attribute__((ext_vector_type(16))) float f32x16;

#define KSCALE 0.18033688011112042f  /* 1/sqrt(64) * log2(e) */

#if __has_builtin(__builtin_amdgcn_exp2f)
#define EXP2(x) __builtin_amdgcn_exp2f(x)
#else
#define EXP2(x) exp2f(x)
#endif

static __device__ __forceinline__ unsigned short f2bf(float f) {
    unsigned int u = __float_as_uint(f);
    u += 0x7FFFu + ((u >> 16) & 1u);   // round-to-nearest-even
    return (unsigned short)(u >> 16);
}

// packed f32->bf16 pair (RTNE), no builtin on gfx950
static __device__ __forceinline__ unsigned int cvtpk(float lo, float hi) {
    unsigned int r;
    asm("v_cvt_pk_bf16_f32 %0, %1, %2" : "=v"(r) : "v"(lo), "v"(hi));
    return r;
}

// x' = [x.row0, y.row0] ; y' = [x.row1, y.row1]  (rows = 32-lane halves)
static __device__ __forceinline__ void plswap(unsigned int& x, unsigned int& y) {
    asm volatile("v_permlane32_swap_b32 %0, %1" : "+v"(x), "+v"(y));
}

// async 16B global -> LDS (wave-uniform lds base + lane*16; global per-lane)
static __device__ __forceinline__ void gll16(const unsigned short* g,
                                             const unsigned short* l) {
    __builtin_amdgcn_global_load_lds(
        (const __attribute__((address_space(1))) unsigned int*)g,
        (__attribute__((address_space(3))) unsigned int*)l,
        16, 0, 0);
}

// ---------------------------------------------------------------------------
// fused fp32 -> bf16 conversion of all six tensors + cumsum (single launch)
// ---------------------------------------------------------------------------
__global__ __launch_bounds__(256) void xattn_convert_all(
    const float* __restrict__ queries, const float* __restrict__ patches,
    const float* __restrict__ wq, const float* __restrict__ wk,
    const float* __restrict__ wv, const float* __restrict__ wo,
    unsigned short* __restrict__ qb, unsigned short* __restrict__ pb,
    unsigned short* __restrict__ wqb, unsigned short* __restrict__ wkb,
    unsigned short* __restrict__ wvb, unsigned short* __restrict__ wob,
    const int* __restrict__ bounds, int* __restrict__ pidx) {
    if (blockIdx.x >= NCONV) {
        // ---- cumsum path: one block per batch, 256 threads x 16 elems ----
        __shared__ int sdata[256];
        int b = blockIdx.x - NCONV;
        int t = threadIdx.x;
        const int* src = bounds + b * S_ + t * 16;
        int vals[16];
        int run = 0;
#pragma unroll
        for (int i = 0; i < 16; ++i) { run += src[i]; vals[i] = run; }
        sdata[t] = run;
        __syncthreads();
        for (int off = 1; off < 256; off <<= 1) {
            int v = (t >= off) ? sdata[t - off] : 0;
            __syncthreads();
            sdata[t] += v;
            __syncthreads();
        }
        int prefix = (t > 0) ? sdata[t - 1] : 0;
        int* dst = pidx + b * S_ + t * 16;
#pragma unroll
        for (int i = 0; i < 16; ++i) dst[i] = prefix + vals[i];
        return;
    }
    // ---- convert path ----
    const int NQ = (B_ * S_ * D_) / 4;      // 2097152
    const int NP = (B_ * P_ * D_) / 4;      // 524288
    const int NW = (D_ * D_) / 4;           // 262144
    int i = blockIdx.x * 256 + threadIdx.x;
    const float* src;
    unsigned short* dst;
    int j;
    if (i < NQ) { src = queries; dst = qb; j = i; }
    else if (i < NQ + NP) { src = patches; dst = pb; j = i - NQ; }
    else {
        int k = i - NQ - NP;
        int wsel = k >> 18;                  // NW = 2^18
        j = k & (NW - 1);
        if (wsel == 0) { src = wq; dst = wqb; }
        else if (wsel == 1) { src = wk; dst = wkb; }
        else if (wsel == 2) { src = wv; dst = wvb; }
        else { src = wo; dst = wob; }
    }
    float4 v = ((const float4*)src)[j];
    ushort4 o;
    o.x = f2bf(v.x); o.y = f2bf(v.y); o.z = f2bf(v.z); o.w = f2bf(v.w);
    ((ushort4*)dst)[j] = o;
}

// ---------------------------------------------------------------------------
// Fused QKV projection: 128Mx256N tile, 8 waves, dbuf gll staging + counted
// vmcnt(3), XOR-swizzled LDS, BK=32. (unchanged from R13)
// Grid dim3(4, 96): y<64 -> Q-proj; y in [64,80) -> K-proj (frag-linear Kf);
//                   y in [80,96) -> V-proj (frag-linear Vf)
// Fragment-linear layouts (per b,h,ptile of 64 patches; 4096 shorts each):
//   Kf: [at(2)][ks(4)][lane(64)][j(8)]   lane=((k>>3)&1)*32+(p&31), j=k&7
//   Vf: [dt(2)][ps(4)][lane(64)][j(8)]   lane=((p>>3)&1)*32+(d&31), j=p&7
// ---------------------------------------------------------------------------
__global__ __launch_bounds__(512) void xattn_gemm_qkv(
    const unsigned short* __restrict__ qb, const unsigned short* __restrict__ pb,
    const unsigned short* __restrict__ wqb, const unsigned short* __restrict__ wkb,
    const unsigned short* __restrict__ wvb,
    const float* __restrict__ bq, const float* __restrict__ bk,
    const float* __restrict__ bv,
    unsigned short* __restrict__ Qout, unsigned short* __restrict__ Kout,
    unsigned short* __restrict__ Vout) {
    const int K = 1024, N = 1024;
    const int byy = blockIdx.y;
    int z, my;
    if (byy < 64)      { z = 0; my = byy; }
    else if (byy < 80) { z = 1; my = byy - 64; }
    else               { z = 2; my = byy - 80; }
    const unsigned short* A = (z == 0) ? qb : pb;
    const unsigned short* W = (z == 0) ? wqb : ((z == 1) ? wkb : wvb);
    const float* bias = (z == 0) ? bq : ((z == 1) ? bk : bv);

    __shared__ unsigned short As[2][128 * 32];
    __shared__ unsigned short Bs[2][256 * 32];

    const int m0 = my * 128;
    const int n0 = blockIdx.x * 256;
    const int t = threadIdx.x;
    const int w = t >> 6;
    const int l = t & 63;
    const int fr = l & 15, fq = l >> 4;
    const int wr = w >> 2, wc = w & 3;

    const int r0s = t >> 2;
    const int csw = ((t & 3) ^ ((t >> 3) & 3)) * 8;   // pre-swizzled source
    const unsigned short* Ap0 = A + (size_t)(m0 + r0s) * K + csw;
    const unsigned short* Wp0 = W + (size_t)(n0 + r0s) * K + csw;
    const unsigned short* Wp1 = W + (size_t)(n0 + 128 + r0s) * K + csw;

    const int gsw = (fq ^ ((fr >> 1) & 3)) * 8;       // swizzled read granule

    f32x4 acc[4][4];
#pragma unroll
    for (int i = 0; i < 4; ++i)
#pragma unroll
        for (int j = 0; j < 4; ++j) acc[i][j] = (f32x4){0.f, 0.f, 0.f, 0.f};

    // prologue: stage K-step 0 into buffer 0
    gll16(Ap0, &As[0][w * 512]);
    gll16(Wp0, &Bs[0][w * 512]);
    gll16(Wp1, &Bs[0][4096 + w * 512]);

    for (int kt = 0; kt < 32; ++kt) {
        __builtin_amdgcn_s_barrier();     // prev iter's readers done
        if (kt + 1 < 32) {
            const int nb = (kt + 1) & 1;
            const int ks = (kt + 1) * 32;
            gll16(Ap0 + ks, &As[nb][w * 512]);
            gll16(Wp0 + ks, &Bs[nb][w * 512]);
            gll16(Wp1 + ks, &Bs[nb][4096 + w * 512]);
            asm volatile("s_waitcnt vmcnt(3)" ::: "memory");
        } else {
            asm volatile("s_waitcnt vmcnt(0)" ::: "memory");
        }
        __builtin_amdgcn_sched_barrier(0);
        __builtin_amdgcn_s_barrier();     // all waves' step-kt stage complete

        const unsigned short* Ac = As[kt & 1];
        const unsigned short* Bc = Bs[kt & 1];
        short8 af[4], bf[4];
#pragma unroll
        for (int i = 0; i < 4; ++i)
            af[i] = *(const short8*)&Ac[(wr * 64 + i * 16 + fr) * 32 + gsw];
#pragma unroll
        for (int j = 0; j < 4; ++j)
            bf[j] = *(const short8*)&Bc[(wc * 64 + j * 16 + fr) * 32 + gsw];
        __builtin_amdgcn_s_setprio(1);
#pragma unroll
        for (int i = 0; i < 4; ++i)
#pragma unroll
            for (int j = 0; j < 4; ++j)
                acc[i][j] = __builtin_amdgcn_mfma_f32_16x16x32_bf16(af[i], bf[j], acc[i][j], 0, 0, 0);
        __builtin_amdgcn_s_setprio(0);
    }

#pragma unroll
    for (int j = 0; j < 4; ++j) {
        int n = n0 + wc * 64 + j * 16 + fr;
        float bvv = bias[n];
#pragma unroll
        for (int i = 0; i < 4; ++i) {
            int mbase = m0 + wr * 64 + i * 16 + fq * 4;
#pragma unroll
            for (int r = 0; r < 4; ++r) {
                float val = acc[i][j][r] + bvv;
                int m = mbase + r;
                if (z == 0) {
                    Qout[(size_t)m * N + n] = f2bf(val * KSCALE);
                } else if (z == 1) {
                    int bb = m >> 10, p = m & (P_ - 1);
                    int hh = n >> 6, k = n & 63;
                    size_t base = ((size_t)((bb * H_ + hh) * 16 + (p >> 6))) * 4096;
                    int off = (((p >> 5) & 1) * 4 + (k >> 4)) * 512 +
                              (((k >> 3) & 1) * 32 + (p & 31)) * 8 + (k & 7);
                    Kout[base + off] = f2bf(val);
                } else {
                    int bb = m >> 10, p = m & (P_ - 1);
                    int hh = n >> 6, d = n & 63;
                    size_t base = ((size_t)((bb * H_ + hh) * 16 + (p >> 6))) * 4096;
                    int off = ((d >> 5) * 4 + ((p >> 4) & 3)) * 512 +
                              ((((p >> 3) & 1) * 32) + (d & 31)) * 8 + (p & 7);
                    Vout[base + off] = f2bf(val);
                }
            }
        }
    }
}

// ---------------------------------------------------------------------------
// O projection: 128Mx256N tile, 8 waves, dbuf gll staging + counted vmcnt(3),
// XOR-swizzled LDS, fp32 out. (unchanged from R13)
// ---------------------------------------------------------------------------
__global__ __launch_bounds__(512) void xattn_gemm_o(
    const unsigned short* __restrict__ A,
    const unsigned short* __restrict__ W,
    const float* __restrict__ bias,
    float* __restrict__ Cout) {
    const int K = 1024, N = 1024;
    __shared__ unsigned short As[2][128 * 32];
    __shared__ unsigned short Bs[2][256 * 32];

    const int m0 = blockIdx.y * 128;
    const int n0 = blockIdx.x * 256;
    const int t = threadIdx.x;
    const int w = t >> 6;
    const int l = t & 63;
    const int fr = l & 15, fq = l >> 4;
    const int wr = w >> 2, wc = w & 3;

    const int r0s = t >> 2;
    const int csw = ((t & 3) ^ ((t >> 3) & 3)) * 8;   // pre-swizzled source
    const unsigned short* Ap0 = A + (size_t)(m0 + r0s) * K + csw;
    const unsigned short* Wp0 = W + (size_t)(n0 + r0s) * K + csw;
    const unsigned short* Wp1 = W + (size_t)(n0 + 128 + r0s) * K + csw;

    const int gsw = (fq ^ ((fr >> 1) & 3)) * 8;       // swizzled read granule

    f32x4 acc[4][4];
#pragma unroll
    for (int i = 0; i < 4; ++i)
#pragma unroll
        for (int j = 0; j < 4; ++j) acc[i][j] = (f32x4){0.f, 0.f, 0.f, 0.f};

    // prologue: stage K-step 0 into buffer 0
    gll16(Ap0, &As[0][w * 512]);
    gll16(Wp0, &Bs[0][w * 512]);
    gll16(Wp1, &Bs[0][4096 + w * 512]);

    for (int kt = 0; kt < 32; ++kt) {
        __builtin_amdgcn_s_barrier();
        if (kt + 1 < 32) {
            const int nb = (kt + 1) & 1;
            const int ks = (kt + 1) * 32;
            gll16(Ap0 + ks, &As[nb][w * 512]);
            gll16(Wp0 + ks, &Bs[nb][w * 512]);
            gll16(Wp1 + ks, &Bs[nb][4096 + w * 512]);
            asm volatile("s_waitcnt vmcnt(3)" ::: "memory");
        } else {
            asm volatile("s_waitcnt vmcnt(0)" ::: "memory");
        }
        __builtin_amdgcn_sched_barrier(0);
        __builtin_amdgcn_s_barrier();

        const unsigned short* Ac = As[kt & 1];
        const unsigned short* Bc = Bs[kt & 1];
        short8 af[4], bf[4];
#pragma unroll
        for (int i = 0; i < 4; ++i)
            af[i] = *(const short8*)&Ac[(wr * 64 + i * 16 + fr) * 32 + gsw];
#pragma unroll
        for (int j = 0; j < 4; ++j)
            bf[j] = *(const short8*)&Bc[(wc * 64 + j * 16 + fr) * 32 + gsw];
        __builtin_amdgcn_s_setprio(1);
#pragma unroll
        for (int i = 0; i < 4; ++i)
#pragma unroll
            for (int j = 0; j < 4; ++j)
                acc[i][j] = __builtin_amdgcn_mfma_f32_16x16x32_bf16(af[i], bf[j], acc[i][j], 0, 0, 0);
        __builtin_amdgcn_s_setprio(0);
    }

#pragma unroll
    for (int j = 0; j < 4; ++j) {
        int n = n0 + wc * 64 + j * 16 + fr;
        float bvv = bias[n];
#pragma unroll
        for (int i = 0; i < 4; ++i) {
            int mbase = m0 + wr * 64 + i * 16 + fq * 4;
#pragma unroll
            for (int r = 0; r < 4; ++r)
                Cout[(size_t)(mbase + r) * N + n] = acc[i][j][r] + bvv;
        }
    }
}

// ---------------------------------------------------------------------------
// MFMA flash attention, round 15: wave-pair patch-split (R14 structure,
// no min-waves launch bound -> no spill).
// 8 waves x 512 thr per 128-q block. Wave w: q-rows (w&3)*32.., role = w>>2.
// Per 64-patch tile, per wave (its 32-patch half only):
//   S^T = mfma(K[role],Q): 4 MFMA32; exp2+mask+lsum on 16 regs;
//   pack 2 pa frags (8 cvtpk + 4 permlane); PV: 4 MFMA32 (2 dt x 2 ps).
// oacc/lsum linear in p -> end-of-block LDS combine (2 x 16KB phases in Ks).
// ---------------------------------------------------------------------------
__global__ __launch_bounds__(512) void xattn_attn_mfma(
    const unsigned short* __restrict__ Qb,   // [B*S][D] bf16 (pre-scaled)
    const unsigned short* __restrict__ Kf,   // frag-linear (see gemm_qkv)
    const unsigned short* __restrict__ Vf,   // frag-linear
    const int* __restrict__ pidx,
    unsigned short* __restrict__ Ob) {       // [B*S][D] bf16
    __shared__ unsigned short Ks[2][4096];
    __shared__ unsigned short Vs[2][4096];

    const int q0 = (31 - blockIdx.x) * 128;  // LPT: heavy blocks first
    const int h = blockIdx.y;
    const int b = blockIdx.z;
    const int t = threadIdx.x;
    const int w = t >> 6, l = t & 63;
    const int lq = l & 31, lh = l >> 5;
    const int wq4 = w & 3, role = w >> 2;    // q-subblock, patch-half role
    const int qw = q0 + wq4 * 32;

    // Q B-frags (col = lq, k = ks*16 + lh*8 + j); both roles load same rows
    const unsigned short* qrow =
        Qb + (size_t)(b * S_ + qw + lq) * D_ + h * DH_ + lh * 8;
    short8 qf[4];
#pragma unroll
    for (int ks = 0; ks < 4; ++ks) qf[ks] = *(const short8*)(qrow + ks * 16);

    const int prow = pidx[b * S_ + qw + lq];        // this lane's q row
    const int limit = pidx[b * S_ + q0 + 127];      // monotone in s
    const int ntiles = (min(limit, P_ - 1) + 64) >> 6;
    const int nfull = (pidx[b * S_ + q0] + 1) >> 6; // tiles needing no mask

    float l4[4] = {0.f, 0.f, 0.f, 0.f};
    f32x16 oacc[2] = {{}, {}};

    // staging: wave w moves chunk w (1KB) of each 8KB frag tile
    const unsigned short* kfb =
        Kf + (size_t)((b * H_ + h) * 16) * 4096 + w * 512 + l * 8;
    const unsigned short* vfb =
        Vf + (size_t)((b * H_ + h) * 16) * 4096 + w * 512 + l * 8;

    // prologue: stage tile 0 into buffer 0 (2 loads/wave)
    gll16(kfb, &Ks[0][w * 512]);
    gll16(vfb, &Vs[0][w * 512]);

    for (int kt = 0; kt < ntiles; ++kt) {
        // B1: all waves done reading buf[kt&1 ^1] -> safe to refill
        __builtin_amdgcn_s_barrier();
        if (kt + 1 < ntiles) {
            const int nb = (kt + 1) & 1;
            gll16(kfb + (size_t)(kt + 1) * 4096, &Ks[nb][w * 512]);
            gll16(vfb + (size_t)(kt + 1) * 4096, &Vs[nb][w * 512]);
            // wait only for tile kt's 2 loads; kt+1's stay in flight
            asm volatile("s_waitcnt vmcnt(2)" ::: "memory");
        } else {
            asm volatile("s_waitcnt vmcnt(0)" ::: "memory");
        }
        __builtin_amdgcn_sched_barrier(0);
        // B2: every wave's tile-kt stage is complete
        __builtin_amdgcn_s_barrier();

        const unsigned short* Kc = Ks[kt & 1];
        const unsigned short* Vc = Vs[kt & 1];
        const int c0 = kt * 64;

        // S^T = K . Q^T, this wave's patch half only (rows p, cols q = lq)
        f32x16 sa = {};
        __builtin_amdgcn_s_setprio(1);
#pragma unroll
        for (int ks = 0; ks < 4; ++ks) {
            short8 kfr = *(const short8*)&Kc[(role * 4 + ks) * 512 + l * 8];
            sa = __builtin_amdgcn_mfma_f32_32x32x16_bf16(kfr, qf[ks], sa, 0, 0, 0);
        }
        __builtin_amdgcn_s_setprio(0);

        // exp2 + boundary mask + lsum (p = c0 + role*32 + crow(r,lh))
        if (kt >= nfull) {
#pragma unroll
            for (int r = 0; r < 16; ++r) {
                const int pg = c0 + role * 32 + (r & 3) + 8 * (r >> 2) + 4 * lh;
                float p = EXP2(sa[r]);
                p = (pg > prow) ? 0.f : p;
                sa[r] = p;
                l4[r & 3] += p;
            }
        } else {
#pragma unroll
            for (int r = 0; r < 16; ++r) {
                float p = EXP2(sa[r]);
                sa[r] = p;
                l4[r & 3] += p;
            }
        }

        // pack P into PV A-frags (this half's 2 ps steps)
        short8 pa[2];
#pragma unroll
        for (int psl = 0; psl < 2; ++psl) {
            const int rA = psl * 8;
            unsigned int X0 = cvtpk(sa[rA + 0], sa[rA + 1]);
            unsigned int Y0 = cvtpk(sa[rA + 4], sa[rA + 5]);
            unsigned int X1 = cvtpk(sa[rA + 2], sa[rA + 3]);
            unsigned int Y1 = cvtpk(sa[rA + 6], sa[rA + 7]);
            plswap(X0, Y0);   // X0 -> word m=0, Y0 -> word m=2
            plswap(X1, Y1);   // X1 -> word m=1, Y1 -> word m=3
            uint4 u = {X0, X1, Y0, Y1};
            pa[psl] = *(short8*)&u;
        }

        // PV partial: O[q][d] += P_half . V_half
        __builtin_amdgcn_s_setprio(1);
#pragma unroll
        for (int dt = 0; dt < 2; ++dt)
#pragma unroll
            for (int psl = 0; psl < 2; ++psl) {
                short8 vfr = *(const short8*)
                    &Vc[(dt * 4 + role * 2 + psl) * 512 + l * 8];
                oacc[dt] = __builtin_amdgcn_mfma_f32_32x32x16_bf16(pa[psl], vfr, oacc[dt], 0, 0, 0);
            }
        __builtin_amdgcn_s_setprio(0);
    }

    // ---- cross-role combine (oacc and lsum are linear in p) ----
    float lsum = (l4[0] + l4[1]) + (l4[2] + l4[3]);  // partial: 16 p-values
    float* cf = (float*)&Ks[0][0];                   // 4096 floats (16KB)
    float* lf = (float*)&Vs[0][0];                   // 256 floats
    const int ci = wq4 * 64 + l;

    __builtin_amdgcn_s_barrier();          // all waves done with K/V LDS
    if (role) {
#pragma unroll
        for (int r = 0; r < 16; ++r) cf[ci * 16 + r] = oacc[0][r];
        lf[ci] = lsum;
    }
    __builtin_amdgcn_s_barrier();
    if (!role) {
#pragma unroll
        for (int r = 0; r < 16; ++r) oacc[0][r] += cf[ci * 16 + r];
        lsum += lf[ci];
    }
    __builtin_amdgcn_s_barrier();
    if (role) {
#pragma unroll
        for (int r = 0; r < 16; ++r) cf[ci * 16 + r] = oacc[1][r];
    }
    __builtin_amdgcn_s_barrier();
    if (!role) {
#pragma unroll
        for (int r = 0; r < 16; ++r) oacc[1][r] += cf[ci * 16 + r];

        // softmax denominator: own half + partner lane's half
        lsum += __shfl_xor(lsum, 32);
        const float inv = 1.0f / lsum;

        unsigned short* ob = Ob + (size_t)(b * S_ + qw) * D_ + h * DH_;
#pragma unroll
        for (int r = 0; r < 16; ++r) {
            const int qr = (r & 3) + 8 * (r >> 2) + 4 * lh;
            const float invr = __shfl(inv, qr);
            ob[(size_t)qr * D_ + lq] = f2bf(oacc[0][r] * invr);
            ob[(size_t)qr * D_ + 32 + lq] = f2bf(oacc[1][r] * invr);
        }
    }
}

// ---------------------------------------------------------------------------
// launch
// ---------------------------------------------------------------------------
extern "C" void kernel_launch(void* const* d_in, const int* in_sizes, int n_in,
                              void* d_out, int out_size, void* d_ws, size_t ws_size,
                              hipStream_t stream) {
    const float* queries = (const float*)d_in[0];
    const float* patches = (const float*)d_in[1];
    const int* bounds    = (const int*)d_in[2];
    const float* wq = (const float*)d_in[3];
    const float* wk = (const float*)d_in[4];
    const float* wv = (const float*)d_in[5];
    const float* wo = (const float*)d_in[6];
    const float* bq = (const float*)d_in[7];
    const float* bk = (const float*)d_in[8];
    const float* bv = (const float*)d_in[9];
    const float* bo = (const float*)d_in[10];
    float* out = (float*)d_out;

    char* ws = (char*)d_ws;
    unsigned short* qb    = (unsigned short*)(ws + 0);          // 16777216
    unsigned short* pb    = (unsigned short*)(ws + 16777216);   // 4194304
    unsigned short* wqb   = (unsigned short*)(ws + 20971520);   // 2097152
    unsigned short* wkb   = (unsigned short*)(ws + 23068672);
    unsigned short* wvb   = (unsigned short*)(ws + 25165824);
    unsigned short* wob   = (unsigned short*)(ws + 27262976);
    unsigned short* Qbf   = (unsigned short*)(ws + 29360128);   // 16777216
    unsigned short* Kfr   = (unsigned short*)(ws + 46137344);   // 4194304
    unsigned short* Vfr   = (unsigned short*)(ws + 50331648);   // 4194304
    unsigned short* attnb = (unsigned short*)(ws + 54525952);   // 16777216
    int* pidx             = (int*)(ws + 71303168);              // 32768

    // 1. fused converts + cumsum
    xattn_convert_all<<<dim3(NCONV + B_), 256, 0, stream>>>(
        queries, patches, wq, wk, wv, wo, qb, pb, wqb, wkb, wvb, wob,
        bounds, pidx);
    // 2. fused Q/K/V projections (128x256 tiles, K/V emitted frag-linear)
    xattn_gemm_qkv<<<dim3(4, 96), 512, 0, stream>>>(
        qb, pb, wqb, wkb, wvb, bq, bk, bv, Qbf, Kfr, Vfr);
    // 3. MFMA flash attention (wave-pair patch-split, 8 waves, no VGPR cap)
    xattn_attn_mfma<<<dim3(S_ / 128, H_, B_), 512, 0, stream>>>(
        Qbf, Kfr, Vfr, pidx, attnb);
    // 4. output projection (128x256 tiles, fp32 out)
    xattn_gemm_o<<<dim3(4, 64), 512, 0, stream>>>(attnb, wob, bo, out);
}